// Round 14
// baseline (151.557 us; speedup 1.0000x reference)
//
#include <hip/hip_runtime.h>
#include <hip/hip_bf16.h>

typedef _Float16 f16;
typedef _Float16 f16x8 __attribute__((ext_vector_type(8)));
typedef _Float16 f16x4 __attribute__((ext_vector_type(4)));
typedef float f32x4 __attribute__((ext_vector_type(4)));
typedef int i32x4 __attribute__((ext_vector_type(4)));

#define B_ 8
#define P_ 2048
#define Q_ 512
#define H_ 1024

__device__ __forceinline__ void gload_lds16(const void* g, void* l) {
  __builtin_amdgcn_global_load_lds(
      (const __attribute__((address_space(1))) void*)g,
      (__attribute__((address_space(3))) void*)l, 16, 0, 0);
}

// ---- f32 -> f16 convert (map_W) ----
__global__ __launch_bounds__(256) void k_cvt16(const float* __restrict__ x,
                                               f16* __restrict__ y, int n4) {
  int i = blockIdx.x * blockDim.x + threadIdx.x;
  int stride = gridDim.x * blockDim.x;
  for (; i < n4; i += stride) {
    f32x4 v = ((const f32x4*)x)[i];
    f16x4 h;
#pragma unroll
    for (int j = 0; j < 4; ++j) h[j] = (f16)v[j];
    ((f16x4*)y)[i] = h;
  }
}

// ---- question [B,Q,H] f32 -> qT [B,H,Q] f16 AND q16 [B,Q,H] f16 ----
__global__ __launch_bounds__(256) void k_transpose(const float* __restrict__ q,
                                                   f16* __restrict__ qT,
                                                   f16* __restrict__ q16) {
  __shared__ float t[64][65];
  int b = blockIdx.z;
  int h0 = blockIdx.x * 64, q0 = blockIdx.y * 64;
  int tid = threadIdx.x;
  int c4 = (tid & 15) * 4;
  int r16 = tid >> 4;
  const float* src = q + ((long)b * Q_ + q0) * H_ + h0;
  f16* d16 = q16 + ((long)b * Q_ + q0) * H_ + h0;
#pragma unroll
  for (int i = 0; i < 4; ++i) {
    int r = r16 + i * 16;
    f32x4 v = *(const f32x4*)(src + (long)r * H_ + c4);
    f16x4 s;
#pragma unroll
    for (int j = 0; j < 4; ++j) s[j] = (f16)v[j];
    *(f16x4*)(d16 + (long)r * H_ + c4) = s;
    t[c4 + 0][r] = v[0];
    t[c4 + 1][r] = v[1];
    t[c4 + 2][r] = v[2];
    t[c4 + 3][r] = v[3];
  }
  __syncthreads();
  f16* dst = qT + ((long)b * H_ + h0) * Q_ + q0;
#pragma unroll
  for (int i = 0; i < 4; ++i) {
    int hr = r16 + i * 16;
    f16x4 o;
#pragma unroll
    for (int j = 0; j < 4; ++j) o[j] = (f16)t[hr][c4 + j];
    *(f16x4*)(dst + (long)hr * Q_ + c4) = o;
  }
}

// ==== GEMM1: S = passage @ question^T, 128x256 tile (R8/R12-proven) ====
__global__ __launch_bounds__(512, 2) void k_gemm1(
    const float* __restrict__ passage, const f16* __restrict__ q16,
    float* __restrict__ S) {
  constexpr int NT = H_ / 32;  // 32 K-tiles
  __shared__ __align__(16) f16 smem[40960];  // 80 KB

  int orig = blockIdx.x;  // 256 blocks: gx=2 (col), gy=16 (row), z=8
  int wg = (orig & 7) * 32 + (orig >> 3);  // T1 bijective; z == XCD
  int bx = wg & 1, by = (wg >> 1) & 15, z = wg >> 5;
  int row0 = by * 128, col0 = bx * 256;

  int tid = threadIdx.x, wv = tid >> 6, lane = tid & 63;
  int fr = lane & 15, kq = lane >> 4;
  int wr = (wv >> 2) * 64, wc = (wv & 3) * 64;
  int swz = (kq ^ ((fr >> 1) & 3)) * 8;

  int ar = tid >> 2, ac = tid & 3;
  const float* gA = passage + ((long)(z * P_ + row0 + ar)) * H_ + ac * 8;
  int aw = ar * 32 + ((ac ^ ((ar >> 1) & 3)) * 8);  // chunk-XOR swizzled

  const f16* gB = q16 + ((long)(z * Q_ + col0 + (tid >> 2))) * H_ +
                  (((tid & 3) ^ ((tid >> 3) & 3)) * 8);

  auto stageB = [&](int t) {
    const f16* g = gB + t * 32;
    f16* l = smem + 8192 + (t & 3) * 8192 + wv * 512;
    gload_lds16(g, l);
    gload_lds16(g + (long)128 * H_, l + 4096);
  };
  auto writeA = [&](int t, f32x4 lo, f32x4 hi) {
    f16x8 h;
#pragma unroll
    for (int j = 0; j < 4; ++j) {
      h[j] = (f16)lo[j];
      h[4 + j] = (f16)hi[j];
    }
    *(f16x8*)(smem + (t & 1) * 4096 + aw) = h;
  };

  f32x4 acc[4][4] = {};
  f32x4 a0lo, a0hi, a1lo, a1hi;  // named regs, static parity (rule 20)

  a0lo = *(const f32x4*)(gA);
  a0hi = *(const f32x4*)(gA + 4);
  a1lo = *(const f32x4*)(gA + 32);
  a1hi = *(const f32x4*)(gA + 36);
  stageB(0);
  stageB(1);
  stageB(2);
  writeA(0, a0lo, a0hi);
  asm volatile("s_waitcnt vmcnt(4) lgkmcnt(0)" ::: "memory");
  __builtin_amdgcn_s_barrier();
  __builtin_amdgcn_sched_barrier(0);

#pragma unroll 4
  for (int t = 0; t < NT; ++t) {
    if (t + 2 < NT) {
      const float* g = gA + (t + 2) * 32;
      if (t & 1) {
        a1lo = *(const f32x4*)(g);
        a1hi = *(const f32x4*)(g + 4);
      } else {
        a0lo = *(const f32x4*)(g);
        a0hi = *(const f32x4*)(g + 4);
      }
    }
    if (t + 3 < NT) stageB(t + 3);
    f16x8 af[4], bf[4];
    const f16* Ab = smem + (t & 1) * 4096;
    const f16* Bb = smem + 8192 + (t & 3) * 8192;
#pragma unroll
    for (int m = 0; m < 4; ++m)
      af[m] = *(const f16x8*)(Ab + (wr + m * 16 + fr) * 32 + swz);
#pragma unroll
    for (int n = 0; n < 4; ++n)
      bf[n] = *(const f16x8*)(Bb + (wc + n * 16 + fr) * 32 + swz);
    if (t + 1 < NT)
      writeA(t + 1, (t & 1) ? a0lo : a1lo, (t & 1) ? a0hi : a1hi);
    __builtin_amdgcn_s_setprio(1);
#pragma unroll
    for (int m = 0; m < 4; ++m)
#pragma unroll
      for (int n = 0; n < 4; ++n)
        acc[m][n] = __builtin_amdgcn_mfma_f32_16x16x32_f16(af[m], bf[n],
                                                           acc[m][n], 0, 0, 0);
    __builtin_amdgcn_s_setprio(0);
    if (t <= NT - 4)
      asm volatile("s_waitcnt vmcnt(6) lgkmcnt(0)" ::: "memory");
    else if (t == NT - 3)
      asm volatile("s_waitcnt vmcnt(4) lgkmcnt(0)" ::: "memory");
    else
      asm volatile("s_waitcnt vmcnt(0) lgkmcnt(0)" ::: "memory");
    if (t < NT - 1) {
      __builtin_amdgcn_s_barrier();
      __builtin_amdgcn_sched_barrier(0);
    }
  }

  float* Sp = S + (long)z * P_ * Q_;
  int r0 = row0 + wr + (lane >> 4) * 4;
  int c0 = col0 + wc + fr;
#pragma unroll
  for (int m = 0; m < 4; ++m)
#pragma unroll
    for (int n = 0; n < 4; ++n)
#pragma unroll
      for (int j = 0; j < 4; ++j)
        Sp[(long)(r0 + m * 16 + j) * Q_ + c0 + n * 16] = acc[m][n][j];
}

// ---- masked softmax (R1-proven): alpha = m*e^{t-c}/(Sum(m*e) + 1e-13*Z) ----
__global__ __launch_bounds__(256) void k_softmax(const float* __restrict__ S,
                                                 const int* __restrict__ qmask,
                                                 f16* __restrict__ alpha) {
  int row = blockIdx.x * 4 + (threadIdx.x >> 6);
  int lane = threadIdx.x & 63;
  int b = row >> 11;  // P_=2048 rows per batch
  const float* s = S + (long)row * Q_;
  const int* mp = qmask + b * Q_;
  f32x4 v0 = ((const f32x4*)s)[lane * 2];
  f32x4 v1 = ((const f32x4*)s)[lane * 2 + 1];
  i32x4 m0 = ((const i32x4*)mp)[lane * 2];
  i32x4 m1 = ((const i32x4*)mp)[lane * 2 + 1];
  float t[8], mf[8];
#pragma unroll
  for (int j = 0; j < 4; ++j) {
    mf[j] = (float)m0[j];     t[j] = v0[j] * mf[j];
    mf[4 + j] = (float)m1[j]; t[4 + j] = v1[j] * mf[4 + j];
  }
  float mx = t[0];
#pragma unroll
  for (int j = 1; j < 8; ++j) mx = fmaxf(mx, t[j]);
  for (int o = 32; o; o >>= 1) mx = fmaxf(mx, __shfl_xor(mx, o, 64));
  float e[8], Z = 0.f, Sm = 0.f;
#pragma unroll
  for (int j = 0; j < 8; ++j) {
    e[j] = expf(t[j] - mx);
    Z += e[j];
    Sm += e[j] * mf[j];
  }
  for (int o = 32; o; o >>= 1) {
    Z += __shfl_xor(Z, o, 64);
    Sm += __shfl_xor(Sm, o, 64);
  }
  float inv = 1.0f / (Sm + 1e-13f * Z);
  f16x8 out;
#pragma unroll
  for (int j = 0; j < 8; ++j) out[j] = (f16)(e[j] * mf[j] * inv);
  *(f16x8*)(alpha + (long)row * Q_ + lane * 8) = out;
}

// ---- 256x256-tile GEMM, BK=64 ring-2 (fewer, fatter K-steps) ----
// Per-step fixed overhead (~2300 cyc: ds_read issue + barrier + waits) was
// the dominant cost at BK=32 (NT steps); BK=64 halves NT. Ring-2 (2x64KB)
// race-free via: all 24 ds_reads of tile t -> lgkmcnt(0)+barrier (reads
// retired in ALL waves) -> stage(t+2) overwrites slot t&1 -> 64 MFMA ->
// counted vmcnt(8) [t+1 landed, t+2's 8 in flight] -> barrier.
// NT = K/64. EPI: 1 = f16 store, 2 = f32 bias+relu nontemporal store.
template <int EPI, int NT>
__global__ __launch_bounds__(512, 2) void k_gemm256(
    const f16* __restrict__ A, const f16* __restrict__ Bm,
    void* __restrict__ Cv, const float* __restrict__ bias, int N, int gx,
    int gy, long sA, long sB, long sC) {
  constexpr int K = NT * 64;
  __shared__ __align__(16) f16 smem[65536];  // 2 slots x 32768 elems (64KB)

  int nwg = gridDim.x;  // 256
  int orig = blockIdx.x;
  int wg = (orig & 7) * (nwg >> 3) + (orig >> 3);  // T1 bijective
  int bx = wg % gx;
  int tt = wg / gx;
  int by = tt % gy;
  int z = tt / gy;
  int row0 = by * 256, col0 = bx * 256;
  A += z * sA;
  Bm += z * sB;

  int tid = threadIdx.x, wv = tid >> 6, lane = tid & 63;

  // staging: 8 rounds of 64 rows x 128B (rounds 0-3: A, 4-7: B). Thread t:
  // row rowR=t>>3 (tile-local, +64/round), stored chunk pos (t&3) in half
  // (t>>2)&1, logical chunk cl = pos ^ ((row>>1)&3) (64-multiples vanish).
  int rowR = tid >> 3;
  int half = (tid >> 2) & 1;
  int cl = (tid & 3) ^ ((rowR >> 1) & 3);
  const f16* gAs = A + (long)(row0 + rowR) * K + half * 32 + cl * 8;
  const f16* gBs = Bm + (long)(col0 + rowR) * K + half * 32 + cl * 8;

  auto stage = [&](int t) {
    f16* l = smem + (t & 1) * 32768 + tid * 8;
    const f16* ga = gAs + (long)t * 64;
    const f16* gb = gBs + (long)t * 64;
#pragma unroll
    for (int j = 0; j < 4; ++j)
      gload_lds16(ga + (long)j * 64 * K, l + j * 4096);
#pragma unroll
    for (int j = 0; j < 4; ++j)
      gload_lds16(gb + (long)j * 64 * K, l + 16384 + j * 4096);
  };

  int wr = (wv >> 2) * 128, wc = (wv & 3) * 64;
  int fr = lane & 15, kq = lane >> 4;
  int swz = (kq ^ ((fr >> 1) & 3)) * 8;

  f32x4 acc[8][4] = {};

  stage(0);
  stage(1);
  asm volatile("s_waitcnt vmcnt(8)" ::: "memory");  // tile 0 landed
  __builtin_amdgcn_s_barrier();
  __builtin_amdgcn_sched_barrier(0);
#pragma unroll 2
  for (int t = 0; t < NT; ++t) {
    const f16* bufA = smem + (t & 1) * 32768;
    const f16* bufB = bufA + 16384;
    f16x8 af0[8], bf0[4], af1[8], bf1[4];
#pragma unroll
    for (int m = 0; m < 8; ++m)
      af0[m] = *(const f16x8*)(bufA + (wr + m * 16 + fr) * 64 + swz);
#pragma unroll
    for (int n = 0; n < 4; ++n)
      bf0[n] = *(const f16x8*)(bufB + (wc + n * 16 + fr) * 64 + swz);
#pragma unroll
    for (int m = 0; m < 8; ++m)
      af1[m] = *(const f16x8*)(bufA + (wr + m * 16 + fr) * 64 + 32 + swz);
#pragma unroll
    for (int n = 0; n < 4; ++n)
      bf1[n] = *(const f16x8*)(bufB + (wc + n * 16 + fr) * 64 + 32 + swz);
    asm volatile("s_waitcnt lgkmcnt(0)" ::: "memory");
    __builtin_amdgcn_sched_barrier(0);
    __builtin_amdgcn_s_barrier();  // all waves' reads of slot t&1 retired
    if (t + 2 < NT) stage(t + 2);  // safe: overwrites fully-read slot
    __builtin_amdgcn_s_setprio(1);
#pragma unroll
    for (int m = 0; m < 8; ++m)
#pragma unroll
      for (int n = 0; n < 4; ++n)
        acc[m][n] = __builtin_amdgcn_mfma_f32_16x16x32_f16(af0[m], bf0[n],
                                                           acc[m][n], 0, 0, 0);
#pragma unroll
    for (int m = 0; m < 8; ++m)
#pragma unroll
      for (int n = 0; n < 4; ++n)
        acc[m][n] = __builtin_amdgcn_mfma_f32_16x16x32_f16(af1[m], bf1[n],
                                                           acc[m][n], 0, 0, 0);
    __builtin_amdgcn_s_setprio(0);
    if (t + 2 < NT)
      asm volatile("s_waitcnt vmcnt(8)" ::: "memory");  // t+1 landed
    else
      asm volatile("s_waitcnt vmcnt(0)" ::: "memory");
    if (t + 1 < NT) {
      __builtin_amdgcn_s_barrier();
      __builtin_amdgcn_sched_barrier(0);
    }
  }

  int r0 = row0 + wr + (lane >> 4) * 4;
  int c0 = col0 + wc + fr;
  if constexpr (EPI == 1) {
    f16* C = (f16*)Cv + z * sC;
#pragma unroll
    for (int m = 0; m < 8; ++m)
#pragma unroll
      for (int n = 0; n < 4; ++n)
#pragma unroll
        for (int j = 0; j < 4; ++j)
          C[(long)(r0 + m * 16 + j) * N + c0 + n * 16] = (f16)acc[m][n][j];
  } else {
    float* C = (float*)Cv;
#pragma unroll
    for (int n = 0; n < 4; ++n) {
      float bv = bias[c0 + n * 16];
#pragma unroll
      for (int m = 0; m < 8; ++m)
#pragma unroll
        for (int j = 0; j < 4; ++j) {
          float v = acc[m][n][j] + bv;
          __builtin_nontemporal_store(
              fmaxf(v, 0.f), &C[(long)(r0 + m * 16 + j) * N + c0 + n * 16]);
        }
    }
  }
}

extern "C" void kernel_launch(void* const* d_in, const int* in_sizes, int n_in,
                              void* d_out, int out_size, void* d_ws,
                              size_t ws_size, hipStream_t stream) {
  const float* passage = (const float*)d_in[0];
  const float* question = (const float*)d_in[1];
  const int* qmask = (const int*)d_in[2];
  const float* mapW = (const float*)d_in[3];
  const float* mapb = (const float*)d_in[4];

  char* ws = (char*)d_ws;
  size_t off = 0;
  auto alloc = [&](size_t bytes) {
    void* p = ws + off;
    off += (bytes + 255) & ~(size_t)255;
    return p;
  };
  f16* q16 = (f16*)alloc((size_t)B_ * Q_ * H_ * 2);
  f16* qT = (f16*)alloc((size_t)B_ * H_ * Q_ * 2);
  f16* w16 = (f16*)alloc((size_t)H_ * H_ * 2);
  f16* alpha = (f16*)alloc((size_t)B_ * P_ * Q_ * 2);
  f16* O = (f16*)alloc((size_t)B_ * P_ * H_ * 2);
  float* S = (float*)alloc((size_t)B_ * P_ * Q_ * 4);

  k_cvt16<<<512, 256, 0, stream>>>(mapW, w16, H_ * H_ / 4);
  k_transpose<<<dim3(H_ / 64, Q_ / 64, B_), 256, 0, stream>>>(question, qT,
                                                              q16);

  // GEMM1: S = passage @ question^T  (2 x 16 x 8 = 256 tiles == 256 blocks)
  k_gemm1<<<256, 512, 0, stream>>>(passage, q16, S);

  // masked softmax -> alpha f16
  k_softmax<<<B_ * P_ / 4, 256, 0, stream>>>(S, qmask, alpha);

  // GEMM3: O = alpha @ question  (4 x 8 x 8 = 256 tiles, NT = 512/64 = 8)
  k_gemm256<1, Q_ / 64><<<256, 512, 0, stream>>>(
      alpha, qT, O, nullptr, H_, H_ / 256, P_ / 256, (long)P_ * Q_,
      (long)H_ * Q_, (long)P_ * H_);

  // GEMM4: Y = relu(O @ W^T + b)  (4 x 64 x 1 = 256 tiles, NT = 1024/64 = 16)
  k_gemm256<2, H_ / 64><<<256, 512, 0, stream>>>(
      O, w16, d_out, mapb, H_, H_ / 256, (B_ * P_) / 256, 0, 0, 0);
}

// Round 15
// 119.440 us; speedup vs baseline: 1.2689x; 1.2689x over previous
//
#include <hip/hip_runtime.h>
#include <hip/hip_bf16.h>

typedef _Float16 f16;
typedef _Float16 f16x8 __attribute__((ext_vector_type(8)));
typedef _Float16 f16x4 __attribute__((ext_vector_type(4)));
typedef float f32x4 __attribute__((ext_vector_type(4)));
typedef int i32x4 __attribute__((ext_vector_type(4)));

#define B_ 8
#define P_ 2048
#define Q_ 512
#define H_ 1024

__device__ __forceinline__ void gload_lds16(const void* g, void* l) {
  __builtin_amdgcn_global_load_lds(
      (const __attribute__((address_space(1))) void*)g,
      (__attribute__((address_space(3))) void*)l, 16, 0, 0);
}

// ---- f32 -> f16 convert (map_W) ----
__global__ __launch_bounds__(256) void k_cvt16(const float* __restrict__ x,
                                               f16* __restrict__ y, int n4) {
  int i = blockIdx.x * blockDim.x + threadIdx.x;
  int stride = gridDim.x * blockDim.x;
  for (; i < n4; i += stride) {
    f32x4 v = ((const f32x4*)x)[i];
    f16x4 h;
#pragma unroll
    for (int j = 0; j < 4; ++j) h[j] = (f16)v[j];
    ((f16x4*)y)[i] = h;
  }
}

// ---- question [B,Q,H] f32 -> qT [B,H,Q] f16 AND q16 [B,Q,H] f16 ----
__global__ __launch_bounds__(256) void k_transpose(const float* __restrict__ q,
                                                   f16* __restrict__ qT,
                                                   f16* __restrict__ q16) {
  __shared__ float t[64][65];
  int b = blockIdx.z;
  int h0 = blockIdx.x * 64, q0 = blockIdx.y * 64;
  int tid = threadIdx.x;
  int c4 = (tid & 15) * 4;
  int r16 = tid >> 4;
  const float* src = q + ((long)b * Q_ + q0) * H_ + h0;
  f16* d16 = q16 + ((long)b * Q_ + q0) * H_ + h0;
#pragma unroll
  for (int i = 0; i < 4; ++i) {
    int r = r16 + i * 16;
    f32x4 v = *(const f32x4*)(src + (long)r * H_ + c4);
    f16x4 s;
#pragma unroll
    for (int j = 0; j < 4; ++j) s[j] = (f16)v[j];
    *(f16x4*)(d16 + (long)r * H_ + c4) = s;
    t[c4 + 0][r] = v[0];
    t[c4 + 1][r] = v[1];
    t[c4 + 2][r] = v[2];
    t[c4 + 3][r] = v[3];
  }
  __syncthreads();
  f16* dst = qT + ((long)b * H_ + h0) * Q_ + q0;
#pragma unroll
  for (int i = 0; i < 4; ++i) {
    int hr = r16 + i * 16;
    f16x4 o;
#pragma unroll
    for (int j = 0; j < 4; ++j) o[j] = (f16)t[hr][c4 + j];
    *(f16x4*)(dst + (long)hr * Q_ + c4) = o;
  }
}

// ==== GEMM1: S = passage @ question^T, 128x256 tile (R8/R12-proven) ====
__global__ __launch_bounds__(512, 2) void k_gemm1(
    const float* __restrict__ passage, const f16* __restrict__ q16,
    float* __restrict__ S) {
  constexpr int NT = H_ / 32;  // 32 K-tiles
  __shared__ __align__(16) f16 smem[40960];  // 80 KB

  int orig = blockIdx.x;  // 256 blocks: gx=2 (col), gy=16 (row), z=8
  int wg = (orig & 7) * 32 + (orig >> 3);  // T1 bijective; z == XCD
  int bx = wg & 1, by = (wg >> 1) & 15, z = wg >> 5;
  int row0 = by * 128, col0 = bx * 256;

  int tid = threadIdx.x, wv = tid >> 6, lane = tid & 63;
  int fr = lane & 15, kq = lane >> 4;
  int wr = (wv >> 2) * 64, wc = (wv & 3) * 64;
  int swz = (kq ^ ((fr >> 1) & 3)) * 8;

  int ar = tid >> 2, ac = tid & 3;
  const float* gA = passage + ((long)(z * P_ + row0 + ar)) * H_ + ac * 8;
  int aw = ar * 32 + ((ac ^ ((ar >> 1) & 3)) * 8);  // chunk-XOR swizzled

  const f16* gB = q16 + ((long)(z * Q_ + col0 + (tid >> 2))) * H_ +
                  (((tid & 3) ^ ((tid >> 3) & 3)) * 8);

  auto stageB = [&](int t) {
    const f16* g = gB + t * 32;
    f16* l = smem + 8192 + (t & 3) * 8192 + wv * 512;
    gload_lds16(g, l);
    gload_lds16(g + (long)128 * H_, l + 4096);
  };
  auto writeA = [&](int t, f32x4 lo, f32x4 hi) {
    f16x8 h;
#pragma unroll
    for (int j = 0; j < 4; ++j) {
      h[j] = (f16)lo[j];
      h[4 + j] = (f16)hi[j];
    }
    *(f16x8*)(smem + (t & 1) * 4096 + aw) = h;
  };

  f32x4 acc[4][4] = {};
  f32x4 a0lo, a0hi, a1lo, a1hi;  // named regs, static parity (rule 20)

  a0lo = *(const f32x4*)(gA);
  a0hi = *(const f32x4*)(gA + 4);
  a1lo = *(const f32x4*)(gA + 32);
  a1hi = *(const f32x4*)(gA + 36);
  stageB(0);
  stageB(1);
  stageB(2);
  writeA(0, a0lo, a0hi);
  asm volatile("s_waitcnt vmcnt(4) lgkmcnt(0)" ::: "memory");
  __builtin_amdgcn_s_barrier();
  __builtin_amdgcn_sched_barrier(0);

#pragma unroll 4
  for (int t = 0; t < NT; ++t) {
    if (t + 2 < NT) {
      const float* g = gA + (t + 2) * 32;
      if (t & 1) {
        a1lo = *(const f32x4*)(g);
        a1hi = *(const f32x4*)(g + 4);
      } else {
        a0lo = *(const f32x4*)(g);
        a0hi = *(const f32x4*)(g + 4);
      }
    }
    if (t + 3 < NT) stageB(t + 3);
    f16x8 af[4], bf[4];
    const f16* Ab = smem + (t & 1) * 4096;
    const f16* Bb = smem + 8192 + (t & 3) * 8192;
#pragma unroll
    for (int m = 0; m < 4; ++m)
      af[m] = *(const f16x8*)(Ab + (wr + m * 16 + fr) * 32 + swz);
#pragma unroll
    for (int n = 0; n < 4; ++n)
      bf[n] = *(const f16x8*)(Bb + (wc + n * 16 + fr) * 32 + swz);
    if (t + 1 < NT)
      writeA(t + 1, (t & 1) ? a0lo : a1lo, (t & 1) ? a0hi : a1hi);
    __builtin_amdgcn_s_setprio(1);
#pragma unroll
    for (int m = 0; m < 4; ++m)
#pragma unroll
      for (int n = 0; n < 4; ++n)
        acc[m][n] = __builtin_amdgcn_mfma_f32_16x16x32_f16(af[m], bf[n],
                                                           acc[m][n], 0, 0, 0);
    __builtin_amdgcn_s_setprio(0);
    if (t <= NT - 4)
      asm volatile("s_waitcnt vmcnt(6) lgkmcnt(0)" ::: "memory");
    else if (t == NT - 3)
      asm volatile("s_waitcnt vmcnt(4) lgkmcnt(0)" ::: "memory");
    else
      asm volatile("s_waitcnt vmcnt(0) lgkmcnt(0)" ::: "memory");
    if (t < NT - 1) {
      __builtin_amdgcn_s_barrier();
      __builtin_amdgcn_sched_barrier(0);
    }
  }

  float* Sp = S + (long)z * P_ * Q_;
  int r0 = row0 + wr + (lane >> 4) * 4;
  int c0 = col0 + wc + fr;
#pragma unroll
  for (int m = 0; m < 4; ++m)
#pragma unroll
    for (int n = 0; n < 4; ++n)
#pragma unroll
      for (int j = 0; j < 4; ++j)
        Sp[(long)(r0 + m * 16 + j) * Q_ + c0 + n * 16] = acc[m][n][j];
}

// ---- masked softmax (R1-proven): alpha = m*e^{t-c}/(Sum(m*e) + 1e-13*Z) ----
__global__ __launch_bounds__(256) void k_softmax(const float* __restrict__ S,
                                                 const int* __restrict__ qmask,
                                                 f16* __restrict__ alpha) {
  int row = blockIdx.x * 4 + (threadIdx.x >> 6);
  int lane = threadIdx.x & 63;
  int b = row >> 11;  // P_=2048 rows per batch
  const float* s = S + (long)row * Q_;
  const int* mp = qmask + b * Q_;
  f32x4 v0 = ((const f32x4*)s)[lane * 2];
  f32x4 v1 = ((const f32x4*)s)[lane * 2 + 1];
  i32x4 m0 = ((const i32x4*)mp)[lane * 2];
  i32x4 m1 = ((const i32x4*)mp)[lane * 2 + 1];
  float t[8], mf[8];
#pragma unroll
  for (int j = 0; j < 4; ++j) {
    mf[j] = (float)m0[j];     t[j] = v0[j] * mf[j];
    mf[4 + j] = (float)m1[j]; t[4 + j] = v1[j] * mf[4 + j];
  }
  float mx = t[0];
#pragma unroll
  for (int j = 1; j < 8; ++j) mx = fmaxf(mx, t[j]);
  for (int o = 32; o; o >>= 1) mx = fmaxf(mx, __shfl_xor(mx, o, 64));
  float e[8], Z = 0.f, Sm = 0.f;
#pragma unroll
  for (int j = 0; j < 8; ++j) {
    e[j] = expf(t[j] - mx);
    Z += e[j];
    Sm += e[j] * mf[j];
  }
  for (int o = 32; o; o >>= 1) {
    Z += __shfl_xor(Z, o, 64);
    Sm += __shfl_xor(Sm, o, 64);
  }
  float inv = 1.0f / (Sm + 1e-13f * Z);
  f16x8 out;
#pragma unroll
  for (int j = 0; j < 8; ++j) out[j] = (f16)(e[j] * mf[j] * inv);
  *(f16x8*)(alpha + (long)row * Q_ + lane * 8) = out;
}

// ---- 256x128-tile GEMM, ring-3, 2 blocks/CU (TLP for overhead hiding) ----
// R12's proven schedule shape (stage-ahead-2 at loop top, counted vmcnt,
// ONE barrier/step, BK=32 proven swizzle) with: tile 256(M)x128(N), unified
// 3-gld staging (R10 k_gemm1 pattern: A rows 0-127, A 128-255, B 0-127),
// ring-3 slots of 24KB -> LDS 72KB -> 2 blocks/CU at 512 blocks. Co-resident
// blocks' MFMAs cover each other's ds_read/barrier overhead (m114).
// Ring-3 safety: stage(t+2) overwrites slot (t+2)%3 = (t-1)%3, whose reads
// all retired before iter t-1's exit barrier.
// Steady vmcnt(3): t+1's 3 glds landed, t+2's 3 in flight.
// EPI: 1 = f16 store, 2 = f32 bias+relu nontemporal store.
template <int EPI, int NT>
__global__ __launch_bounds__(512, 4) void k_gemm256(
    const f16* __restrict__ A, const f16* __restrict__ Bm,
    void* __restrict__ Cv, const float* __restrict__ bias, int N, int gx,
    int gy, long sA, long sB, long sC) {
  constexpr int K = NT * 32;
  constexpr int SLOT = 12288;  // f16 elems per ring slot (24KB)
  __shared__ __align__(16) f16 smem[3 * SLOT];  // 72KB

  int nwg = gridDim.x;  // 512
  int orig = blockIdx.x;
  int wg = (orig & 7) * (nwg >> 3) + (orig >> 3);  // T1 bijective
  int bx = wg % gx;
  int tt = wg / gx;
  int by = tt % gy;
  int z = tt / gy;
  int row0 = by * 256, col0 = bx * 128;
  A += z * sA;
  Bm += z * sB;

  int tid = threadIdx.x, wv = tid >> 6, lane = tid & 63;
  int fr = lane & 15, kq = lane >> 4;

  // unified staging (R10-proven): 3 rounds of 128 rows x 64B; 4 lanes/row,
  // chunk pre-swizzled on the global source (rule 21; 0 conflicts R10/R12).
  int scl = ((tid & 3) ^ ((tid >> 3) & 3)) * 8;
  int R0 = tid >> 2;
  const f16* g0 = A + (long)(row0 + R0) * K + scl;
  const f16* g1 = A + (long)(row0 + 128 + R0) * K + scl;
  const f16* g2 = Bm + (long)(col0 + R0) * K + scl;

  auto stage = [&](int t) {
    f16* l = smem + (t % 3) * SLOT + wv * 512;
    gload_lds16(g0 + t * 32, l);
    gload_lds16(g1 + t * 32, l + 4096);
    gload_lds16(g2 + t * 32, l + 8192);
  };

  // waves 2M x 4N over 256x128: wave rows (wv>>2)*128 (8 m-frags),
  // cols (wv&3)*32 (2 n-frags)
  int wr = (wv >> 2) * 128, wc = (wv & 3) * 32;
  int swz = (kq ^ ((fr >> 1) & 3)) * 8 + fr * 32;

  f32x4 acc[8][2] = {};
  auto compute = [&](int t) {
    const f16* bufA = smem + (t % 3) * SLOT;
    const f16* bufB = bufA + 8192;
    f16x8 af[8], bfr[2];
#pragma unroll
    for (int m = 0; m < 8; ++m)
      af[m] = *(const f16x8*)(bufA + (wr + m * 16) * 32 + swz);
#pragma unroll
    for (int n = 0; n < 2; ++n)
      bfr[n] = *(const f16x8*)(bufB + (wc + n * 16) * 32 + swz);
    __builtin_amdgcn_s_setprio(1);
#pragma unroll
    for (int m = 0; m < 8; ++m)
#pragma unroll
      for (int n = 0; n < 2; ++n)
        acc[m][n] = __builtin_amdgcn_mfma_f32_16x16x32_f16(af[m], bfr[n],
                                                           acc[m][n], 0, 0, 0);
    __builtin_amdgcn_s_setprio(0);
  };

  stage(0);
  stage(1);
  asm volatile("s_waitcnt vmcnt(3)" ::: "memory");  // tile 0 landed
  __builtin_amdgcn_s_barrier();
  __builtin_amdgcn_sched_barrier(0);
  for (int t = 0; t < NT; ++t) {
    if (t + 2 < NT) stage(t + 2);  // slot (t+2)%3: reads retired pre t-1 exit
    compute(t);
    if (t + 2 < NT)
      asm volatile("s_waitcnt vmcnt(3)" ::: "memory");  // t+1 landed
    else
      asm volatile("s_waitcnt vmcnt(0)" ::: "memory");
    if (t + 1 < NT) {
      __builtin_amdgcn_s_barrier();
      __builtin_amdgcn_sched_barrier(0);
    }
  }

  int r0 = row0 + wr + (lane >> 4) * 4;
  int c0 = col0 + wc + fr;
  if constexpr (EPI == 1) {
    f16* C = (f16*)Cv + z * sC;
#pragma unroll
    for (int m = 0; m < 8; ++m)
#pragma unroll
      for (int n = 0; n < 2; ++n)
#pragma unroll
        for (int j = 0; j < 4; ++j)
          C[(long)(r0 + m * 16 + j) * N + c0 + n * 16] = (f16)acc[m][n][j];
  } else {
    float* C = (float*)Cv;
#pragma unroll
    for (int n = 0; n < 2; ++n) {
      float bv = bias[c0 + n * 16];
#pragma unroll
      for (int m = 0; m < 8; ++m)
#pragma unroll
        for (int j = 0; j < 4; ++j) {
          float v = acc[m][n][j] + bv;
          __builtin_nontemporal_store(
              fmaxf(v, 0.f), &C[(long)(r0 + m * 16 + j) * N + c0 + n * 16]);
        }
    }
  }
}

extern "C" void kernel_launch(void* const* d_in, const int* in_sizes, int n_in,
                              void* d_out, int out_size, void* d_ws,
                              size_t ws_size, hipStream_t stream) {
  const float* passage = (const float*)d_in[0];
  const float* question = (const float*)d_in[1];
  const int* qmask = (const int*)d_in[2];
  const float* mapW = (const float*)d_in[3];
  const float* mapb = (const float*)d_in[4];

  char* ws = (char*)d_ws;
  size_t off = 0;
  auto alloc = [&](size_t bytes) {
    void* p = ws + off;
    off += (bytes + 255) & ~(size_t)255;
    return p;
  };
  f16* q16 = (f16*)alloc((size_t)B_ * Q_ * H_ * 2);
  f16* qT = (f16*)alloc((size_t)B_ * H_ * Q_ * 2);
  f16* w16 = (f16*)alloc((size_t)H_ * H_ * 2);
  f16* alpha = (f16*)alloc((size_t)B_ * P_ * Q_ * 2);
  f16* O = (f16*)alloc((size_t)B_ * P_ * H_ * 2);
  float* S = (float*)alloc((size_t)B_ * P_ * Q_ * 4);

  k_cvt16<<<512, 256, 0, stream>>>(mapW, w16, H_ * H_ / 4);
  k_transpose<<<dim3(H_ / 64, Q_ / 64, B_), 256, 0, stream>>>(question, qT,
                                                              q16);

  // GEMM1: S = passage @ question^T  (2 x 16 x 8 = 256 tiles == 256 blocks)
  k_gemm1<<<256, 512, 0, stream>>>(passage, q16, S);

  // masked softmax -> alpha f16
  k_softmax<<<B_ * P_ / 4, 256, 0, stream>>>(S, qmask, alpha);

  // GEMM3: O = alpha @ question  (gx=8, gy=8, z=8 -> 512 tiles == 512 blocks)
  k_gemm256<1, Q_ / 32><<<512, 512, 0, stream>>>(
      alpha, qT, O, nullptr, H_, H_ / 128, P_ / 256, (long)P_ * Q_,
      (long)H_ * Q_, (long)P_ * H_);

  // GEMM4: Y = relu(O @ W^T + b)  (gx=8, gy=64, z=1 -> 512 tiles == 512 blocks)
  k_gemm256<2, H_ / 32><<<512, 512, 0, stream>>>(
      O, w16, d_out, mapb, H_, H_ / 128, (B_ * P_) / 256, 0, 0, 0);
}